// Round 2
// baseline (462.684 us; speedup 1.0000x reference)
//
#include <hip/hip_runtime.h>
#include <hip/hip_bf16.h>
#include <cstdint>
#include <cstddef>

// B=2, S=2048, D=512, H=8, DK=64
#define BB 2
#define SS 2048
#define DD 512
#define HH 8
#define DKK 64

typedef __attribute__((ext_vector_type(8))) short bf16x8;   // 8 bf16 = 4 VGPRs
typedef __attribute__((ext_vector_type(4))) float f32x4;

__device__ __forceinline__ unsigned short f2bf(float f) {
    union { float f; unsigned u; } v; v.f = f;
    unsigned u = v.u;
    return (unsigned short)((u + 0x7fffu + ((u >> 16) & 1u)) >> 16);   // RNE
}
__device__ __forceinline__ unsigned pack2(float a, float b) {
    return (unsigned)f2bf(a) | ((unsigned)f2bf(b) << 16);
}

typedef const __attribute__((address_space(1))) unsigned int* gp_t;
typedef __attribute__((address_space(3))) unsigned int* lp_t;
__device__ __forceinline__ void gload_lds16(const void* g, void* l) {
    __builtin_amdgcn_global_load_lds((gp_t)g, (lp_t)l, 16, 0, 0);
}

// ---------------------------------------------------------------------------
// Kernel 0: fp32 -> bf16 conversion. X,Wq,Wk,Wv into P-region scratch;
// Wo into workspace (it must survive the P-write phase of k_attn2).
// ---------------------------------------------------------------------------
__global__ __launch_bounds__(256) void k_cvt(
    const float* __restrict__ q, const float* __restrict__ k, const float* __restrict__ v,
    const float* __restrict__ wq, const float* __restrict__ wk, const float* __restrict__ wv,
    const float* __restrict__ wo, unsigned short* __restrict__ dst,
    unsigned short* __restrict__ dwo)
{
    const size_t NX = (size_t)BB * SS * DD;   // 2,097,152
    const size_t NW = (size_t)DD * DD;        // 262,144
    const int y = blockIdx.y;
    const float* src; unsigned short* d; int n;
    switch (y) {
        case 0: src = q;  d = dst;                 n = (int)NX; break;
        case 1: src = k;  d = dst + NX;            n = (int)NX; break;
        case 2: src = v;  d = dst + 2 * NX;        n = (int)NX; break;
        case 3: src = wq; d = dst + 3 * NX;        n = (int)NW; break;
        case 4: src = wk; d = dst + 3 * NX + NW;   n = (int)NW; break;
        case 5: src = wv; d = dst + 3 * NX + 2*NW; n = (int)NW; break;
        default: src = wo; d = dwo;                n = (int)NW; break;
    }
    int idx = (blockIdx.x * 256 + threadIdx.x) * 8;
    if (idx >= n) return;
    float4 a = *(const float4*)(src + idx);
    float4 b = *(const float4*)(src + idx + 4);
    *(uint4*)(d + idx) = make_uint4(pack2(a.x,a.y), pack2(a.z,a.w), pack2(b.x,b.y), pack2(b.z,b.w));
}

// ---------------------------------------------------------------------------
// Shared 64x64-tile bf16 NT GEMM mainloop (BK=64, global_load_lds,
// XOR-swizzled LDS). acc[nt] = sum_k A[m,k]*W[n,k].
// ---------------------------------------------------------------------------
__device__ __forceinline__ void gemm64_core(
    const unsigned short* __restrict__ A, const unsigned short* __restrict__ W,
    unsigned short* smem, int bm, int bn, int tid, f32x4 acc[4])
{
    const int w = tid >> 6, lane = tid & 63, quad = lane >> 4, l15 = lane & 15;
    for (int k0 = 0; k0 < DD; k0 += 64) {
        #pragma unroll
        for (int r = 0; r < 2; ++r) {
            int flat = r * 256 + tid;
            int row = flat >> 3, c = flat & 7, cs = c ^ (row & 7);
            gload_lds16(A + (size_t)(bm * 64 + row) * DD + k0 + cs * 8, &smem[flat * 8]);
        }
        #pragma unroll
        for (int r = 0; r < 2; ++r) {
            int flat = r * 256 + tid;
            int row = flat >> 3, c = flat & 7, cs = c ^ (row & 7);
            gload_lds16(W + (size_t)(bn * 64 + row) * DD + k0 + cs * 8, &smem[4096 + flat * 8]);
        }
        __syncthreads();
        int mrow = w * 16 + l15;
        bf16x8 a0 = *(const bf16x8*)&smem[(mrow * 8 + (quad ^ (mrow & 7))) * 8];
        bf16x8 a1 = *(const bf16x8*)&smem[(mrow * 8 + ((quad + 4) ^ (mrow & 7))) * 8];
        #pragma unroll
        for (int nt = 0; nt < 4; ++nt) {
            int nrow = nt * 16 + l15;
            bf16x8 b0 = *(const bf16x8*)&smem[4096 + (nrow * 8 + (quad ^ (nrow & 7))) * 8];
            bf16x8 b1 = *(const bf16x8*)&smem[4096 + (nrow * 8 + ((quad + 4) ^ (nrow & 7))) * 8];
            acc[nt] = __builtin_amdgcn_mfma_f32_16x16x32_bf16(a0, b0, acc[nt], 0, 0, 0);
            acc[nt] = __builtin_amdgcn_mfma_f32_16x16x32_bf16(a1, b1, acc[nt], 0, 0, 0);
        }
        __syncthreads();
    }
}

// ---------------------------------------------------------------------------
// Kernel 1: fused Q/K/V projection GEMMs. grid (64, 8, 3) = 1536 blocks.
//  z=0: Q (scale 1/8, head-split bf16)  z=1: K (head-split bf16)
//  z=2: V (transpose -> Vt [bh][dk][s])
// ---------------------------------------------------------------------------
__global__ __launch_bounds__(256) void k_gemm_qkv(
    const unsigned short* __restrict__ scratch,
    unsigned short* __restrict__ Qw, unsigned short* __restrict__ Kw,
    unsigned short* __restrict__ Vt)
{
    __shared__ unsigned short smem[8192];
    const size_t NX = (size_t)BB * SS * DD, NW = (size_t)DD * DD;
    const int z = blockIdx.z;
    const unsigned short* A = scratch + (size_t)z * NX;
    const unsigned short* W = scratch + 3 * NX + (size_t)z * NW;
    const int bm = blockIdx.x, bn = blockIdx.y;
    const int tid = threadIdx.x, w = tid >> 6, lane = tid & 63, quad = lane >> 4, l15 = lane & 15;

    f32x4 acc[4];
    #pragma unroll
    for (int i = 0; i < 4; ++i) acc[i] = (f32x4){0.f, 0.f, 0.f, 0.f};
    gemm64_core(A, W, smem, bm, bn, tid, acc);

    if (z != 2) {
        const float sc = (z == 0) ? 0.125f : 1.0f;
        unsigned short* dbf = (z == 0) ? Qw : Kw;
        #pragma unroll
        for (int nt = 0; nt < 4; ++nt) {
            int n = bn * 64 + nt * 16 + l15;
            int h = n >> 6, dk = n & 63;
            #pragma unroll
            for (int rg = 0; rg < 4; ++rg) {
                int m = bm * 64 + w * 16 + quad * 4 + rg;
                int b = m >> 11, s = m & (SS - 1);
                dbf[(((size_t)(b * HH + h) * SS + s) << 6) + dk] = f2bf(acc[nt][rg] * sc);
            }
        }
    } else {
        unsigned short* T = smem;   // [64][72] = 9216 B, fits in 16 KB
        #pragma unroll
        for (int nt = 0; nt < 4; ++nt)
            #pragma unroll
            for (int rg = 0; rg < 4; ++rg)
                T[(w * 16 + quad * 4 + rg) * 72 + nt * 16 + l15] = f2bf(acc[nt][rg]);
        __syncthreads();
        int n = tid >> 2, s0 = (tid & 3) * 16;
        int ng = bn * 64 + n, h = ng >> 6, dk = ng & 63;
        int mg = bm * 64 + s0, b = mg >> 11, s = mg & (SS - 1);
        unsigned vals[8];
        #pragma unroll
        for (int i = 0; i < 8; ++i)
            vals[i] = (unsigned)T[(s0 + 2*i) * 72 + n] | ((unsigned)T[(s0 + 2*i + 1) * 72 + n] << 16);
        unsigned short* dp = Vt + ((size_t)(b * HH + h) * DKK + dk) * SS + s;
        ((uint4*)dp)[0] = make_uint4(vals[0], vals[1], vals[2], vals[3]);
        ((uint4*)dp)[1] = make_uint4(vals[4], vals[5], vals[6], vals[7]);
    }
}

// ---------------------------------------------------------------------------
// Kernel 2: fused attention core + p_attn writer. Q pre-scaled by 1/8.
// Latency-bound at 2 waves/SIMD (grid-capped) -> explicit register
// double-buffering: issue kt+1's K/V loads before computing kt, with two
// NAMED register buffer sets (static indexing; loop stepped by 2).
// ---------------------------------------------------------------------------
__global__ __launch_bounds__(256) void k_attn2(
    const unsigned short* __restrict__ Qw, const unsigned short* __restrict__ Kw,
    const unsigned short* __restrict__ Vt, unsigned short* __restrict__ AO,
    float* __restrict__ P)
{
    __shared__ unsigned short Pl[2][4][16][68];
    const int qt = blockIdx.x, bh = blockIdx.y;
    const int tid = threadIdx.x, w = tid >> 6, lane = tid & 63, quad = lane >> 4, l15 = lane & 15;

    const unsigned short* Qb = Qw + ((size_t)bh * SS + qt * 64 + w * 16) * DKK;
    const unsigned short* Kb = Kw + (size_t)bh * SS * DKK;
    const unsigned short* Vb = Vt + (size_t)bh * DKK * SS;

    bf16x8 qa0 = *(const bf16x8*)&Qb[l15 * DKK + quad * 8];
    bf16x8 qa1 = *(const bf16x8*)&Qb[l15 * DKK + 32 + quad * 8];

    f32x4 oacc[4];
    #pragma unroll
    for (int i = 0; i < 4; ++i) oacc[i] = (f32x4){0.f, 0.f, 0.f, 0.f};
    float lsum[4] = {0.f, 0.f, 0.f, 0.f};

    // register K/V tile buffers (two named sets; only constant indices)
    bf16x8 kA0[4], kA1[4], vA0[4], vA1[4];
    bf16x8 kB0[4], kB1[4], vB0[4], vB1[4];

    auto loadK = [&](int kt, bf16x8 (&d0)[4], bf16x8 (&d1)[4]) {
        const unsigned short* Kt = Kb + (size_t)kt * 64 * DKK;
        #pragma unroll
        for (int jt = 0; jt < 4; ++jt) {
            d0[jt] = *(const bf16x8*)&Kt[(jt * 16 + l15) * DKK + quad * 8];
            d1[jt] = *(const bf16x8*)&Kt[(jt * 16 + l15) * DKK + 32 + quad * 8];
        }
    };
    auto loadV = [&](int kt, bf16x8 (&d0)[4], bf16x8 (&d1)[4]) {
        #pragma unroll
        for (int dt = 0; dt < 4; ++dt) {
            const unsigned short* Vp = Vb + (size_t)(dt * 16 + l15) * SS + kt * 64;
            d0[dt] = *(const bf16x8*)&Vp[quad * 8];
            d1[dt] = *(const bf16x8*)&Vp[32 + quad * 8];
        }
    };

    // phase-1 compute body for one kt tile, using current regs; LDS buf static
    auto attn_body = [&](int kt, int buf,
                         bf16x8 (&kc0)[4], bf16x8 (&kc1)[4],
                         bf16x8 (&vc0)[4], bf16x8 (&vc1)[4]) {
        f32x4 sa[4];
        #pragma unroll
        for (int i = 0; i < 4; ++i) sa[i] = (f32x4){0.f, 0.f, 0.f, 0.f};
        #pragma unroll
        for (int jt = 0; jt < 4; ++jt) {
            sa[jt] = __builtin_amdgcn_mfma_f32_16x16x32_bf16(qa0, kc0[jt], sa[jt], 0, 0, 0);
            sa[jt] = __builtin_amdgcn_mfma_f32_16x16x32_bf16(qa1, kc1[jt], sa[jt], 0, 0, 0);
        }
        float ev[4][4];
        #pragma unroll
        for (int jt = 0; jt < 4; ++jt)
            #pragma unroll
            for (int rg = 0; rg < 4; ++rg)
                ev[jt][rg] = __expf(sa[jt][rg]);
        #pragma unroll
        for (int rg = 0; rg < 4; ++rg) {
            float s = ev[0][rg] + ev[1][rg] + ev[2][rg] + ev[3][rg];
            s += __shfl_xor(s, 1);
            s += __shfl_xor(s, 2);
            s += __shfl_xor(s, 4);
            s += __shfl_xor(s, 8);
            lsum[rg] += s;
        }
        #pragma unroll
        for (int jt = 0; jt < 4; ++jt)
            #pragma unroll
            for (int rg = 0; rg < 4; ++rg)
                Pl[buf][w][quad * 4 + rg][jt * 16 + l15] = f2bf(ev[jt][rg]);
        bf16x8 pa0 = *(const bf16x8*)&Pl[buf][w][l15][quad * 8];
        bf16x8 pa1 = *(const bf16x8*)&Pl[buf][w][l15][32 + quad * 8];
        #pragma unroll
        for (int dt = 0; dt < 4; ++dt) {
            oacc[dt] = __builtin_amdgcn_mfma_f32_16x16x32_bf16(pa0, vc0[dt], oacc[dt], 0, 0, 0);
            oacc[dt] = __builtin_amdgcn_mfma_f32_16x16x32_bf16(pa1, vc1[dt], oacc[dt], 0, 0, 0);
        }
    };

    // prologue: tile 0 into set A
    loadK(0, kA0, kA1);
    loadV(0, vA0, vA1);
    for (int kt = 0; kt < SS / 64; kt += 2) {
        // body A: prefetch kt+1 into B, compute kt from A
        loadK(kt + 1, kB0, kB1);
        loadV(kt + 1, vB0, vB1);
        attn_body(kt, 0, kA0, kA1, vA0, vA1);
        // body B: prefetch kt+2 into A (wrap on last, result unused), compute kt+1 from B
        int ktn = (kt + 2) & (SS / 64 - 1);
        loadK(ktn, kA0, kA1);
        loadV(ktn, vA0, vA1);
        attn_body(kt + 1, 1, kB0, kB1, vB0, vB1);
    }

    float linv[4];
    #pragma unroll
    for (int rg = 0; rg < 4; ++rg) linv[rg] = 1.0f / lsum[rg];

    const int b = bh >> 3, h = bh & 7;
    const int srow = qt * 64 + w * 16 + quad * 4;
    #pragma unroll
    for (int dt = 0; dt < 4; ++dt)
        #pragma unroll
        for (int rg = 0; rg < 4; ++rg)
            AO[((size_t)(b * SS + srow + rg) << 9) + h * 64 + dt * 16 + l15] =
                f2bf(oacc[dt][rg] * linv[rg]);

    // ------------------ phase 2: stream normalized P ------------------
    float* Pb = P + (((size_t)bh * SS + srow) << 11);
    auto pw_body = [&](int kt, bf16x8 (&kc0)[4], bf16x8 (&kc1)[4]) {
        #pragma unroll
        for (int jt = 0; jt < 4; ++jt) {
            f32x4 sa = (f32x4){0.f, 0.f, 0.f, 0.f};
            sa = __builtin_amdgcn_mfma_f32_16x16x32_bf16(qa0, kc0[jt], sa, 0, 0, 0);
            sa = __builtin_amdgcn_mfma_f32_16x16x32_bf16(qa1, kc1[jt], sa, 0, 0, 0);
            #pragma unroll
            for (int rg = 0; rg < 4; ++rg)
                __builtin_nontemporal_store(__expf(sa[rg]) * linv[rg],
                    &Pb[((size_t)rg << 11) + kt * 64 + jt * 16 + l15]);
        }
    };

    loadK(0, kA0, kA1);
    for (int kt = 0; kt < SS / 64; kt += 2) {
        loadK(kt + 1, kB0, kB1);
        pw_body(kt, kA0, kA1);
        int ktn = (kt + 2) & (SS / 64 - 1);
        loadK(ktn, kA0, kA1);
        pw_body(kt + 1, kB0, kB1);
    }
}

// ---------------------------------------------------------------------------
// Kernel 3: output projection (fp32 row-major epilogue).
// ---------------------------------------------------------------------------
__global__ __launch_bounds__(256) void k_gemm_o(
    const unsigned short* __restrict__ A, const unsigned short* __restrict__ W,
    float* __restrict__ out)
{
    __shared__ unsigned short smem[8192];
    const int bm = blockIdx.x, bn = blockIdx.y;
    const int tid = threadIdx.x, w = tid >> 6, lane = tid & 63, quad = lane >> 4, l15 = lane & 15;
    f32x4 acc[4];
    #pragma unroll
    for (int i = 0; i < 4; ++i) acc[i] = (f32x4){0.f, 0.f, 0.f, 0.f};
    gemm64_core(A, W, smem, bm, bn, tid, acc);
    #pragma unroll
    for (int nt = 0; nt < 4; ++nt)
        #pragma unroll
        for (int rg = 0; rg < 4; ++rg)
            out[(size_t)(bm * 64 + w * 16 + quad * 4 + rg) * DD + bn * 64 + nt * 16 + l15] =
                acc[nt][rg];
}

extern "C" void kernel_launch(void* const* d_in, const int* in_sizes, int n_in,
                              void* d_out, int out_size, void* d_ws, size_t ws_size,
                              hipStream_t stream) {
    const float* q  = (const float*)d_in[0];
    const float* k  = (const float*)d_in[1];
    const float* v  = (const float*)d_in[2];
    const float* wq = (const float*)d_in[3];
    const float* wk = (const float*)d_in[4];
    const float* wv = (const float*)d_in[5];
    const float* wo = (const float*)d_in[6];

    float* out = (float*)d_out;                         // [4096, 512] fp32
    float* P   = out + (size_t)BB * SS * DD;            // [2,8,2048,2048] fp32

    const size_t NX = (size_t)BB * SS * DD;   // 2,097,152
    const size_t NW = (size_t)DD * DD;        // 262,144

    // P-region scratch: ONLY data that is dead before k_attn2 writes P.
    unsigned short* scratch = (unsigned short*)P;       // 3*NX + 3*NW shorts

    // d_ws: everything that must survive the P-write (16.5 MB).
    unsigned short* Qw  = (unsigned short*)d_ws;
    unsigned short* Kw  = Qw + NX;
    unsigned short* Vt  = Kw + NX;
    unsigned short* AO  = Vt + NX;
    unsigned short* Wo2 = AO + NX;

    k_cvt<<<dim3(1024, 7), 256, 0, stream>>>(q, k, v, wq, wk, wv, wo, scratch, Wo2);
    k_gemm_qkv<<<dim3(64, 8, 3), 256, 0, stream>>>(scratch, Qw, Kw, Vt);
    k_attn2<<<dim3(SS / 64, BB * HH), 256, 0, stream>>>(Qw, Kw, Vt, AO, P);
    k_gemm_o<<<dim3(64, 8), 256, 0, stream>>>(AO, Wo2, out);
}

// Round 3
// 393.515 us; speedup vs baseline: 1.1758x; 1.1758x over previous
//
#include <hip/hip_runtime.h>
#include <hip/hip_bf16.h>
#include <cstdint>
#include <cstddef>

// B=2, S=2048, D=512, H=8, DK=64
#define BB 2
#define SS 2048
#define DD 512
#define HH 8
#define DKK 64

typedef __attribute__((ext_vector_type(8))) short bf16x8;   // 8 bf16 = 4 VGPRs
typedef __attribute__((ext_vector_type(4))) float f32x4;

__device__ __forceinline__ unsigned short f2bf(float f) {
    union { float f; unsigned u; } v; v.f = f;
    unsigned u = v.u;
    return (unsigned short)((u + 0x7fffu + ((u >> 16) & 1u)) >> 16);   // RNE
}
__device__ __forceinline__ unsigned pack2(float a, float b) {
    return (unsigned)f2bf(a) | ((unsigned)f2bf(b) << 16);
}

typedef const __attribute__((address_space(1))) unsigned int* gp_t;
typedef __attribute__((address_space(3))) unsigned int* lp_t;
__device__ __forceinline__ void gload_lds16(const void* g, void* l) {
    __builtin_amdgcn_global_load_lds((gp_t)g, (lp_t)l, 16, 0, 0);
}

#define VM_WAIT4 asm volatile("s_waitcnt vmcnt(4)" ::: "memory")
#define VM_WAIT0 asm volatile("s_waitcnt vmcnt(0)" ::: "memory")

// ---------------------------------------------------------------------------
// Kernel 0: fp32 -> bf16 conversion. X,Wq,Wk,Wv into P-region scratch;
// Wo into workspace (survives the P-write).
// ---------------------------------------------------------------------------
__global__ __launch_bounds__(256) void k_cvt(
    const float* __restrict__ q, const float* __restrict__ k, const float* __restrict__ v,
    const float* __restrict__ wq, const float* __restrict__ wk, const float* __restrict__ wv,
    const float* __restrict__ wo, unsigned short* __restrict__ dst,
    unsigned short* __restrict__ dwo)
{
    const size_t NX = (size_t)BB * SS * DD;   // 2,097,152
    const size_t NW = (size_t)DD * DD;        // 262,144
    const int y = blockIdx.y;
    const float* src; unsigned short* d; int n;
    switch (y) {
        case 0: src = q;  d = dst;                 n = (int)NX; break;
        case 1: src = k;  d = dst + NX;            n = (int)NX; break;
        case 2: src = v;  d = dst + 2 * NX;        n = (int)NX; break;
        case 3: src = wq; d = dst + 3 * NX;        n = (int)NW; break;
        case 4: src = wk; d = dst + 3 * NX + NW;   n = (int)NW; break;
        case 5: src = wv; d = dst + 3 * NX + 2*NW; n = (int)NW; break;
        default: src = wo; d = dwo;                n = (int)NW; break;
    }
    int idx = (blockIdx.x * 256 + threadIdx.x) * 8;
    if (idx >= n) return;
    float4 a = *(const float4*)(src + idx);
    float4 b = *(const float4*)(src + idx + 4);
    *(uint4*)(d + idx) = make_uint4(pack2(a.x,a.y), pack2(a.z,a.w), pack2(b.x,b.y), pack2(b.z,b.w));
}

// ---------------------------------------------------------------------------
// Shared 64x64-tile bf16 NT GEMM mainloop (BK=64, global_load_lds,
// XOR-swizzled LDS). acc[nt] = sum_k A[m,k]*W[n,k].
// ---------------------------------------------------------------------------
__device__ __forceinline__ void gemm64_core(
    const unsigned short* __restrict__ A, const unsigned short* __restrict__ W,
    unsigned short* smem, int bm, int bn, int tid, f32x4 acc[4])
{
    const int w = tid >> 6, lane = tid & 63, quad = lane >> 4, l15 = lane & 15;
    for (int k0 = 0; k0 < DD; k0 += 64) {
        #pragma unroll
        for (int r = 0; r < 2; ++r) {
            int flat = r * 256 + tid;
            int row = flat >> 3, c = flat & 7, cs = c ^ (row & 7);
            gload_lds16(A + (size_t)(bm * 64 + row) * DD + k0 + cs * 8, &smem[flat * 8]);
        }
        #pragma unroll
        for (int r = 0; r < 2; ++r) {
            int flat = r * 256 + tid;
            int row = flat >> 3, c = flat & 7, cs = c ^ (row & 7);
            gload_lds16(W + (size_t)(bn * 64 + row) * DD + k0 + cs * 8, &smem[4096 + flat * 8]);
        }
        __syncthreads();
        int mrow = w * 16 + l15;
        bf16x8 a0 = *(const bf16x8*)&smem[(mrow * 8 + (quad ^ (mrow & 7))) * 8];
        bf16x8 a1 = *(const bf16x8*)&smem[(mrow * 8 + ((quad + 4) ^ (mrow & 7))) * 8];
        #pragma unroll
        for (int nt = 0; nt < 4; ++nt) {
            int nrow = nt * 16 + l15;
            bf16x8 b0 = *(const bf16x8*)&smem[4096 + (nrow * 8 + (quad ^ (nrow & 7))) * 8];
            bf16x8 b1 = *(const bf16x8*)&smem[4096 + (nrow * 8 + ((quad + 4) ^ (nrow & 7))) * 8];
            acc[nt] = __builtin_amdgcn_mfma_f32_16x16x32_bf16(a0, b0, acc[nt], 0, 0, 0);
            acc[nt] = __builtin_amdgcn_mfma_f32_16x16x32_bf16(a1, b1, acc[nt], 0, 0, 0);
        }
        __syncthreads();
    }
}

// ---------------------------------------------------------------------------
// Kernel 1: fused Q/K/V projection GEMMs. grid (64, 8, 3) = 1536 blocks.
//  z=0: Q (scale 1/8, head-split bf16)  z=1: K (head-split bf16)
//  z=2: V (transpose -> Vt [bh][dk][s])
// ---------------------------------------------------------------------------
__global__ __launch_bounds__(256) void k_gemm_qkv(
    const unsigned short* __restrict__ scratch,
    unsigned short* __restrict__ Qw, unsigned short* __restrict__ Kw,
    unsigned short* __restrict__ Vt)
{
    __shared__ unsigned short smem[8192];
    const size_t NX = (size_t)BB * SS * DD, NW = (size_t)DD * DD;
    const int z = blockIdx.z;
    const unsigned short* A = scratch + (size_t)z * NX;
    const unsigned short* W = scratch + 3 * NX + (size_t)z * NW;
    const int bm = blockIdx.x, bn = blockIdx.y;
    const int tid = threadIdx.x, w = tid >> 6, lane = tid & 63, quad = lane >> 4, l15 = lane & 15;

    f32x4 acc[4];
    #pragma unroll
    for (int i = 0; i < 4; ++i) acc[i] = (f32x4){0.f, 0.f, 0.f, 0.f};
    gemm64_core(A, W, smem, bm, bn, tid, acc);

    if (z != 2) {
        const float sc = (z == 0) ? 0.125f : 1.0f;
        unsigned short* dbf = (z == 0) ? Qw : Kw;
        #pragma unroll
        for (int nt = 0; nt < 4; ++nt) {
            int n = bn * 64 + nt * 16 + l15;
            int h = n >> 6, dk = n & 63;
            #pragma unroll
            for (int rg = 0; rg < 4; ++rg) {
                int m = bm * 64 + w * 16 + quad * 4 + rg;
                int b = m >> 11, s = m & (SS - 1);
                dbf[(((size_t)(b * HH + h) * SS + s) << 6) + dk] = f2bf(acc[nt][rg] * sc);
            }
        }
    } else {
        unsigned short* T = smem;   // [64][72] = 9216 B, fits in 16 KB
        #pragma unroll
        for (int nt = 0; nt < 4; ++nt)
            #pragma unroll
            for (int rg = 0; rg < 4; ++rg)
                T[(w * 16 + quad * 4 + rg) * 72 + nt * 16 + l15] = f2bf(acc[nt][rg]);
        __syncthreads();
        int n = tid >> 2, s0 = (tid & 3) * 16;
        int ng = bn * 64 + n, h = ng >> 6, dk = ng & 63;
        int mg = bm * 64 + s0, b = mg >> 11, s = mg & (SS - 1);
        unsigned vals[8];
        #pragma unroll
        for (int i = 0; i < 8; ++i)
            vals[i] = (unsigned)T[(s0 + 2*i) * 72 + n] | ((unsigned)T[(s0 + 2*i + 1) * 72 + n] << 16);
        unsigned short* dp = Vt + ((size_t)(b * HH + h) * DKK + dk) * SS + s;
        ((uint4*)dp)[0] = make_uint4(vals[0], vals[1], vals[2], vals[3]);
        ((uint4*)dp)[1] = make_uint4(vals[4], vals[5], vals[6], vals[7]);
    }
}

// ---------------------------------------------------------------------------
// Kernel 2: attention pass 1. Q pre-scaled by 1/8.
// - XCD-locality swizzle: all 32 qt-blocks of one bh land on one XCD
//   (K+V = 512 KB -> L2-resident).
// - K,V staged ONCE per block in LDS (4 waves share; 4x less cache traffic),
//   double-buffered with counted vmcnt(4) + raw s_barrier (loads stay in
//   flight across barriers; never drained to 0 in the main loop).
// Emits AO (bf16, ws) and Linv (fp32, ws).
// ---------------------------------------------------------------------------
__global__ __launch_bounds__(256) void k_attn(
    const unsigned short* __restrict__ Qw, const unsigned short* __restrict__ Kw,
    const unsigned short* __restrict__ Vt, unsigned short* __restrict__ AO,
    float* __restrict__ Linv)
{
    __shared__ unsigned short Kl[2][4096];      // [buf][64 s][64 dk] swizzled, 8 KB/buf
    __shared__ unsigned short Vl[2][4096];      // [buf][64 dk][64 s] swizzled
    __shared__ unsigned short Pl[2][4][16][68]; // per-wave P round-trip

    const int id = blockIdx.x;                  // 512 blocks
    const int xcd = id & 7, j = id >> 3;
    const int bh = xcd * 2 + (j >> 5), qt = j & 31;

    const int tid = threadIdx.x, w = tid >> 6, lane = tid & 63, quad = lane >> 4, l15 = lane & 15;

    const unsigned short* Qb = Qw + ((size_t)bh * SS + qt * 64 + w * 16) * DKK;
    const unsigned short* Kb = Kw + (size_t)bh * SS * DKK;
    const unsigned short* Vb = Vt + (size_t)bh * DKK * SS;

    bf16x8 qa0 = *(const bf16x8*)&Qb[l15 * DKK + quad * 8];
    bf16x8 qa1 = *(const bf16x8*)&Qb[l15 * DKK + 32 + quad * 8];

    f32x4 oacc[4];
    #pragma unroll
    for (int i = 0; i < 4; ++i) oacc[i] = (f32x4){0.f, 0.f, 0.f, 0.f};
    float lsum[4] = {0.f, 0.f, 0.f, 0.f};

    // stage one 64-key tile (K: 8 KB, V: 8 KB) -> 4 gload_lds16 per thread
    auto stage = [&](int kt, int b) {
        #pragma unroll
        for (int r = 0; r < 2; ++r) {
            int flat = r * 256 + tid;
            int row = flat >> 3, c = flat & 7, cs = c ^ (row & 7);
            gload_lds16(Kb + (size_t)(kt * 64 + row) * DKK + cs * 8, &Kl[b][flat * 8]);
        }
        #pragma unroll
        for (int r = 0; r < 2; ++r) {
            int flat = r * 256 + tid;
            int row = flat >> 3, c = flat & 7, cs = c ^ (row & 7);
            gload_lds16(Vb + (size_t)row * SS + kt * 64 + cs * 8, &Vl[b][flat * 8]);
        }
    };

    stage(0, 0);
    stage(1, 1);

    const int NT = SS / 64;   // 32
    for (int kt = 0; kt < NT; ++kt) {
        if (kt < NT - 1) { VM_WAIT4; } else { VM_WAIT0; }   // tile kt staged
        __builtin_amdgcn_s_barrier();
        __builtin_amdgcn_sched_barrier(0);
        const int b = kt & 1;

        f32x4 sa[4];
        #pragma unroll
        for (int i = 0; i < 4; ++i) sa[i] = (f32x4){0.f, 0.f, 0.f, 0.f};
        __builtin_amdgcn_s_setprio(1);
        #pragma unroll
        for (int jt = 0; jt < 4; ++jt) {
            int row = jt * 16 + l15;
            bf16x8 b0 = *(const bf16x8*)&Kl[b][(row * 8 + (quad ^ (row & 7))) * 8];
            bf16x8 b1 = *(const bf16x8*)&Kl[b][(row * 8 + ((quad + 4) ^ (row & 7))) * 8];
            sa[jt] = __builtin_amdgcn_mfma_f32_16x16x32_bf16(qa0, b0, sa[jt], 0, 0, 0);
            sa[jt] = __builtin_amdgcn_mfma_f32_16x16x32_bf16(qa1, b1, sa[jt], 0, 0, 0);
        }
        __builtin_amdgcn_s_setprio(0);

        float ev[4][4];
        #pragma unroll
        for (int jt = 0; jt < 4; ++jt)
            #pragma unroll
            for (int rg = 0; rg < 4; ++rg)
                ev[jt][rg] = __expf(sa[jt][rg]);
        #pragma unroll
        for (int rg = 0; rg < 4; ++rg) {
            float s = ev[0][rg] + ev[1][rg] + ev[2][rg] + ev[3][rg];
            s += __shfl_xor(s, 1);
            s += __shfl_xor(s, 2);
            s += __shfl_xor(s, 4);
            s += __shfl_xor(s, 8);
            lsum[rg] += s;
        }
        #pragma unroll
        for (int jt = 0; jt < 4; ++jt)
            #pragma unroll
            for (int rg = 0; rg < 4; ++rg)
                Pl[b][w][quad * 4 + rg][jt * 16 + l15] = f2bf(ev[jt][rg]);
        bf16x8 pa0 = *(const bf16x8*)&Pl[b][w][l15][quad * 8];
        bf16x8 pa1 = *(const bf16x8*)&Pl[b][w][l15][32 + quad * 8];

        __builtin_amdgcn_s_setprio(1);
        #pragma unroll
        for (int dt = 0; dt < 4; ++dt) {
            int row = dt * 16 + l15;
            bf16x8 v0 = *(const bf16x8*)&Vl[b][(row * 8 + (quad ^ (row & 7))) * 8];
            bf16x8 v1 = *(const bf16x8*)&Vl[b][(row * 8 + ((quad + 4) ^ (row & 7))) * 8];
            oacc[dt] = __builtin_amdgcn_mfma_f32_16x16x32_bf16(pa0, v0, oacc[dt], 0, 0, 0);
            oacc[dt] = __builtin_amdgcn_mfma_f32_16x16x32_bf16(pa1, v1, oacc[dt], 0, 0, 0);
        }
        __builtin_amdgcn_s_setprio(0);

        __builtin_amdgcn_s_barrier();           // all waves done with buf b
        if (kt + 2 < NT) stage(kt + 2, b);      // overwrite buf b with tile kt+2
    }

    float linv[4];
    #pragma unroll
    for (int rg = 0; rg < 4; ++rg) linv[rg] = 1.0f / lsum[rg];

    const int b2 = bh >> 3, h = bh & 7;
    const int srow = qt * 64 + w * 16 + quad * 4;
    #pragma unroll
    for (int dt = 0; dt < 4; ++dt)
        #pragma unroll
        for (int rg = 0; rg < 4; ++rg)
            AO[((size_t)(b2 * SS + srow + rg) << 9) + h * 64 + dt * 16 + l15] =
                f2bf(oacc[dt][rg] * linv[rg]);

    if (l15 == 0) {
        #pragma unroll
        for (int rg = 0; rg < 4; ++rg)
            Linv[(size_t)bh * SS + srow + rg] = linv[rg];
    }
}

// ---------------------------------------------------------------------------
// Kernel 3: p_attn writer. 2048 blocks (8/CU -> TLP hides L2 latency),
// XCD-swizzled so each XCD serves 2 bh (K L2-hot). Stores are float4
// full-line via per-wave LDS transpose (16 lanes cover 256B/row).
// ---------------------------------------------------------------------------
__global__ __launch_bounds__(256) void k_pwrite(
    const unsigned short* __restrict__ Qw, const unsigned short* __restrict__ Kw,
    const float* __restrict__ Linv, float* __restrict__ P)
{
    __shared__ float Tl[4][16][68];             // per-wave transpose tile, 17408 B
    const int id = blockIdx.x;                  // 2048 blocks
    const int xcd = id & 7, j = id >> 3;        // j in [0,256)
    const int bh = xcd * 2 + (j >> 7);
    const int rem = j & 127, qt = rem >> 2, ks = rem & 3;
    const int tid = threadIdx.x, w = tid >> 6, lane = tid & 63, quad = lane >> 4, l15 = lane & 15;

    const unsigned short* Qb = Qw + ((size_t)bh * SS + qt * 64 + w * 16) * DKK;
    bf16x8 qa0 = *(const bf16x8*)&Qb[l15 * DKK + quad * 8];
    bf16x8 qa1 = *(const bf16x8*)&Qb[l15 * DKK + 32 + quad * 8];

    float linv[4];
    #pragma unroll
    for (int rg = 0; rg < 4; ++rg)
        linv[rg] = Linv[(size_t)bh * SS + qt * 64 + w * 16 + quad * 4 + rg];

    const unsigned short* Kb = Kw + (size_t)bh * SS * DKK + (size_t)ks * 512 * DKK;
    float* Pb = P + (((size_t)bh * SS + qt * 64 + w * 16) << 11) + ks * 512;

    for (int kt = 0; kt < 8; ++kt) {
        const unsigned short* Kt = Kb + (size_t)kt * 64 * DKK;
        #pragma unroll
        for (int jt = 0; jt < 4; ++jt) {
            bf16x8 b0 = *(const bf16x8*)&Kt[(jt * 16 + l15) * DKK + quad * 8];
            bf16x8 b1 = *(const bf16x8*)&Kt[(jt * 16 + l15) * DKK + 32 + quad * 8];
            f32x4 sa = (f32x4){0.f, 0.f, 0.f, 0.f};
            sa = __builtin_amdgcn_mfma_f32_16x16x32_bf16(qa0, b0, sa, 0, 0, 0);
            sa = __builtin_amdgcn_mfma_f32_16x16x32_bf16(qa1, b1, sa, 0, 0, 0);
            #pragma unroll
            for (int rg = 0; rg < 4; ++rg)
                Tl[w][quad * 4 + rg][jt * 16 + l15] = __expf(sa[rg]) * linv[rg];
        }
        // transpose: 16 lanes per row -> 256B contiguous float4 stores
        #pragma unroll
        for (int c = 0; c < 4; ++c) {
            int row = c * 4 + quad;
            f32x4 val = *(const f32x4*)&Tl[w][row][l15 * 4];
            __builtin_nontemporal_store(val,
                (f32x4*)(Pb + ((size_t)row << 11) + kt * 64 + l15 * 4));
        }
    }
}

// ---------------------------------------------------------------------------
// Kernel 4: output projection (fp32 row-major epilogue).
// ---------------------------------------------------------------------------
__global__ __launch_bounds__(256) void k_gemm_o(
    const unsigned short* __restrict__ A, const unsigned short* __restrict__ W,
    float* __restrict__ out)
{
    __shared__ unsigned short smem[8192];
    const int bm = blockIdx.x, bn = blockIdx.y;
    const int tid = threadIdx.x, w = tid >> 6, lane = tid & 63, quad = lane >> 4, l15 = lane & 15;
    f32x4 acc[4];
    #pragma unroll
    for (int i = 0; i < 4; ++i) acc[i] = (f32x4){0.f, 0.f, 0.f, 0.f};
    gemm64_core(A, W, smem, bm, bn, tid, acc);
    #pragma unroll
    for (int nt = 0; nt < 4; ++nt)
        #pragma unroll
        for (int rg = 0; rg < 4; ++rg)
            out[(size_t)(bm * 64 + w * 16 + quad * 4 + rg) * DD + bn * 64 + nt * 16 + l15] =
                acc[nt][rg];
}

extern "C" void kernel_launch(void* const* d_in, const int* in_sizes, int n_in,
                              void* d_out, int out_size, void* d_ws, size_t ws_size,
                              hipStream_t stream) {
    const float* q  = (const float*)d_in[0];
    const float* k  = (const float*)d_in[1];
    const float* v  = (const float*)d_in[2];
    const float* wq = (const float*)d_in[3];
    const float* wk = (const float*)d_in[4];
    const float* wv = (const float*)d_in[5];
    const float* wo = (const float*)d_in[6];

    float* out = (float*)d_out;                         // [4096, 512] fp32
    float* P   = out + (size_t)BB * SS * DD;            // [2,8,2048,2048] fp32

    const size_t NX = (size_t)BB * SS * DD;   // 2,097,152
    const size_t NW = (size_t)DD * DD;        // 262,144

    // P-region scratch: ONLY data dead before k_pwrite writes P
    // (X/Wq/Wk/Wv, consumed by k_gemm_qkv).
    unsigned short* scratch = (unsigned short*)P;

    // d_ws: everything that must survive the P-write (~16.7 MB).
    unsigned short* Qw   = (unsigned short*)d_ws;
    unsigned short* Kw   = Qw + NX;
    unsigned short* Vt   = Kw + NX;
    unsigned short* AO   = Vt + NX;
    unsigned short* Wo2  = AO + NX;
    float*          Linv = (float*)(Wo2 + NW);          // [bh][s], 128 KB

    k_cvt<<<dim3(1024, 7), 256, 0, stream>>>(q, k, v, wq, wk, wv, wo, scratch, Wo2);
    k_gemm_qkv<<<dim3(64, 8, 3), 256, 0, stream>>>(scratch, Qw, Kw, Vt);
    k_attn<<<dim3(512), 256, 0, stream>>>(Qw, Kw, Vt, AO, Linv);
    k_pwrite<<<dim3(2048), 256, 0, stream>>>(Qw, Kw, Linv, P);
    k_gemm_o<<<dim3(64, 8), 256, 0, stream>>>(AO, Wo2, out);
}